// Round 5
// baseline (24.498 us; speedup 1.0000x reference)
//
#include <hip/hip_runtime.h>
#include <math.h>

constexpr int DIM = 16;
constexpr int NB  = 16;    // batch rows per block (one per 16-lane group)
constexpr int NST = 8;     // sample tiles
constexpr int BT  = 256;   // threads per block

// ---------------------------------------------------------------------------
// score: block (bt, st). 16 lane-groups; group g owns batch row bt*16+g with
// coefficients in registers, scans the st-th 512-sample tile (32 rows/thread).
//   score(b,s) = sum_d ( c[b,d]*p^2 + a[b,d]*p ),  p = prior[s,d]
//   a = mu/sigma^2, c = 0.5*(1 - 1/sigma^2)   (per-b const dropped; nlp absorbed)
// Partial argmax -> part[b*NST + st].
// ---------------------------------------------------------------------------
__global__ __launch_bounds__(BT) void score_kernel(
    const float* __restrict__ mu_q, const float* __restrict__ std_q,
    const float* __restrict__ prior, float2* __restrict__ part,
    int n_samples)
{
    const int tid = threadIdx.x;
    const int g   = tid >> 4;               // batch row within block
    const int j   = tid & 15;               // lane within group
    const int b   = blockIdx.x * NB + g;
    const int spt = n_samples / NST;        // 512
    const int s0  = blockIdx.y * spt;

    // ---- coefficients for row b, in registers ----
    float a[DIM], c[DIM];
    {
        const float4* mv = reinterpret_cast<const float4*>(mu_q  + (size_t)b * DIM);
        const float4* sv = reinterpret_cast<const float4*>(std_q + (size_t)b * DIM);
#pragma unroll
        for (int i = 0; i < 4; ++i) {
            float4 m4 = mv[i], s4 = sv[i];
            float w;
            w = 1.0f / (s4.x * s4.x); a[4*i+0] = m4.x * w; c[4*i+0] = 0.5f - 0.5f * w;
            w = 1.0f / (s4.y * s4.y); a[4*i+1] = m4.y * w; c[4*i+1] = 0.5f - 0.5f * w;
            w = 1.0f / (s4.z * s4.z); a[4*i+2] = m4.z * w; c[4*i+2] = 0.5f - 0.5f * w;
            w = 1.0f / (s4.w * s4.w); a[4*i+3] = m4.w * w; c[4*i+3] = 0.5f - 0.5f * w;
        }
    }

    float best = -INFINITY; int bidx = 0x7fffffff;

    for (int k = 0; k < spt / 16; ++k) {    // 32 iterations, s ascending
        const int s = s0 + k * 16 + j;
        const float4* rp = reinterpret_cast<const float4*>(prior + (size_t)s * DIM);
        float4 q0 = rp[0], q1 = rp[1], q2 = rp[2], q3 = rp[3];
        float p[DIM] = { q0.x, q0.y, q0.z, q0.w,  q1.x, q1.y, q1.z, q1.w,
                         q2.x, q2.y, q2.z, q2.w,  q3.x, q3.y, q3.z, q3.w };
        float accA = 0.0f, accB = 0.0f;     // two chains (ILP), same as R3
#pragma unroll
        for (int d = 0; d < 8; ++d) {
            accA = fmaf(p[d],   fmaf(c[d],   p[d],   a[d]),   accA);
            accB = fmaf(p[d+8], fmaf(c[d+8], p[d+8], a[d+8]), accB);
        }
        const float sc = accA + accB;
        if (sc > best) { best = sc; bidx = s; }   // strict '>': first max kept
    }

    // ---- reduce across the 16-lane group (offsets stay inside the group) ----
#pragma unroll
    for (int off = 8; off >= 1; off >>= 1) {
        const float ob = __shfl_xor(best, off, 64);
        const int   oi = __shfl_xor(bidx, off, 64);
        if (ob > best || (ob == best && oi < bidx)) { best = ob; bidx = oi; }
    }

    if (j == 0)
        part[(size_t)b * NST + blockIdx.y] = make_float2(best, __int_as_float(bidx));
}

// ---------------------------------------------------------------------------
// merge: one thread per batch row; argmax over NST partials; gather prior row.
// ---------------------------------------------------------------------------
__global__ __launch_bounds__(BT) void merge_kernel(
    const float2* __restrict__ part, const float* __restrict__ prior,
    float* __restrict__ out_samples, float* __restrict__ out_idx, int bs)
{
    const int b = blockIdx.x * BT + threadIdx.x;
    if (b >= bs) return;
    const float2* pb = part + (size_t)b * NST;
    float bb = -INFINITY; int bbi = 0x7fffffff;
#pragma unroll
    for (int t = 0; t < NST; ++t) {
        const float2 v = pb[t];
        const int    i = __float_as_int(v.y);
        if (v.x > bb || (v.x == bb && i < bbi)) { bb = v.x; bbi = i; }
    }
    out_idx[b] = (float)bbi;
    const float4* r4 = reinterpret_cast<const float4*>(prior + (size_t)bbi * DIM);
    float4* o = reinterpret_cast<float4*>(out_samples + (size_t)b * DIM);
    o[0] = r4[0]; o[1] = r4[1]; o[2] = r4[2]; o[3] = r4[3];
}

extern "C" void kernel_launch(void* const* d_in, const int* in_sizes, int n_in,
                              void* d_out, int out_size, void* d_ws, size_t ws_size,
                              hipStream_t stream)
{
    const float* mu_q  = (const float*)d_in[0];   // [bs,16]
    const float* std_q = (const float*)d_in[1];   // [bs,16]
    const float* prior = (const float*)d_in[2];   // [n,16]
    // d_in[3] (normal_log_prob) algebraically absorbed -- unused.

    const int bs        = in_sizes[0] / DIM;      // 1024
    const int n_samples = in_sizes[2] / DIM;      // 4096

    float*  out_samples = (float*)d_out;                      // [bs,16]
    float*  out_idx     = (float*)d_out + (size_t)bs * DIM;   // [bs]
    float2* part        = (float2*)d_ws;                      // [bs][NST]

    dim3 grid(bs / NB, NST);                      // 64 x 8 = 512 blocks
    score_kernel<<<grid, BT, 0, stream>>>(mu_q, std_q, prior, part, n_samples);

    merge_kernel<<<(bs + BT - 1) / BT, BT, 0, stream>>>(
        part, prior, out_samples, out_idx, bs);
}

// Round 6
// 16.311 us; speedup vs baseline: 1.5020x; 1.5020x over previous
//
#include <hip/hip_runtime.h>
#include <math.h>

constexpr int DIM = 16;
constexpr int NB  = 4;     // batch rows per block (coefficients in registers)
constexpr int BT  = 512;   // threads per block -> 8 waves/CU, 2 waves/SIMD
constexpr int NW  = BT / 64;

// ---------------------------------------------------------------------------
// Single fused kernel (one dispatch -- launch overhead dominates this op).
//   score(b,s) = sum_d ( c[b,d]*p^2 + a[b,d]*p ),  p = prior[s,d]
//   a = mu/sigma^2, c = 0.5*(1 - 1/sigma^2)
// (reference's perturbed[b,s] up to a per-b additive constant -- argmax-
//  invariant; normal_log_prob algebraically absorbed: nlp = -0.5 p^2 - K.)
// Block owns NB batch rows end-to-end; scans ALL n_samples prior rows.
// ---------------------------------------------------------------------------
__global__ __launch_bounds__(BT) void pfr_fused_kernel(
    const float* __restrict__ mu_q, const float* __restrict__ std_q,
    const float* __restrict__ prior,
    float* __restrict__ out_samples, float* __restrict__ out_idx,
    int n_samples, int bs)
{
    const int b0  = blockIdx.x * NB;
    const int tid = threadIdx.x;

    // ---- per-block coefficients in registers (block-uniform addresses) ----
    float a[NB][DIM], c[NB][DIM];
#pragma unroll
    for (int r = 0; r < NB; ++r) {
        const int bb = b0 + r;
#pragma unroll
        for (int d = 0; d < DIM; ++d) {
            const float sd = std_q[bb * DIM + d];
            const float w  = 1.0f / (sd * sd);
            a[r][d] = mu_q[bb * DIM + d] * w;
            c[r][d] = 0.5f - 0.5f * w;
        }
    }

    float best[NB]; int bidx[NB];
#pragma unroll
    for (int r = 0; r < NB; ++r) { best[r] = -INFINITY; bidx[r] = 0x7fffffff; }

    // ---- scan: each thread handles n/BT = 8 sample rows, shared across NB ----
    for (int s = tid; s < n_samples; s += BT) {
        const float4* rp = reinterpret_cast<const float4*>(prior + (size_t)s * DIM);
        float4 q0 = rp[0], q1 = rp[1], q2 = rp[2], q3 = rp[3];
        float p[DIM] = { q0.x, q0.y, q0.z, q0.w,  q1.x, q1.y, q1.z, q1.w,
                         q2.x, q2.y, q2.z, q2.w,  q3.x, q3.y, q3.z, q3.w };
#pragma unroll
        for (int r = 0; r < NB; ++r) {
            float accA = 0.0f, accB = 0.0f;          // two chains (same as R3)
#pragma unroll
            for (int d = 0; d < 8; ++d) {
                accA = fmaf(p[d],   fmaf(c[r][d],   p[d],   a[r][d]),   accA);
                accB = fmaf(p[d+8], fmaf(c[r][d+8], p[d+8], a[r][d+8]), accB);
            }
            const float sc = accA + accB;
            // s ascends per thread -> strict '>' keeps first (smallest) idx
            if (sc > best[r]) { best[r] = sc; bidx[r] = s; }
        }
    }

    // ---- wave (64-lane) butterfly, explicit smaller-idx tie-break ----
#pragma unroll
    for (int off = 32; off >= 1; off >>= 1) {
#pragma unroll
        for (int r = 0; r < NB; ++r) {
            const float ob = __shfl_xor(best[r], off, 64);
            const int   oi = __shfl_xor(bidx[r], off, 64);
            if (ob > best[r] || (ob == best[r] && oi < bidx[r])) {
                best[r] = ob; bidx[r] = oi;
            }
        }
    }

    // ---- cross-wave merge via tiny LDS ----
    __shared__ float wv[NW][NB];
    __shared__ int   wi[NW][NB];
    const int wave = tid >> 6;
    if ((tid & 63) == 0) {
#pragma unroll
        for (int r = 0; r < NB; ++r) { wv[wave][r] = best[r]; wi[wave][r] = bidx[r]; }
    }
    __syncthreads();

    if (tid < NB && (b0 + tid) < bs) {
        float bb = wv[0][tid]; int bbi = wi[0][tid];
#pragma unroll
        for (int w = 1; w < NW; ++w) {
            const float ob = wv[w][tid]; const int oi = wi[w][tid];
            if (ob > bb || (ob == bb && oi < bbi)) { bb = ob; bbi = oi; }
        }
        out_idx[b0 + tid] = (float)bbi;
        const float4* r4 = reinterpret_cast<const float4*>(prior + (size_t)bbi * DIM);
        float4* o = reinterpret_cast<float4*>(out_samples + (size_t)(b0 + tid) * DIM);
        o[0] = r4[0]; o[1] = r4[1]; o[2] = r4[2]; o[3] = r4[3];
    }
}

extern "C" void kernel_launch(void* const* d_in, const int* in_sizes, int n_in,
                              void* d_out, int out_size, void* d_ws, size_t ws_size,
                              hipStream_t stream)
{
    const float* mu_q  = (const float*)d_in[0];   // [bs,16]
    const float* std_q = (const float*)d_in[1];   // [bs,16]
    const float* prior = (const float*)d_in[2];   // [n,16]
    // d_in[3] (normal_log_prob) algebraically absorbed -- unused.

    const int bs        = in_sizes[0] / DIM;      // 1024
    const int n_samples = in_sizes[2] / DIM;      // 4096

    float* out_samples = (float*)d_out;                       // [bs,16]
    float* out_idx     = (float*)d_out + (size_t)bs * DIM;    // [bs]

    const int nblocks = (bs + NB - 1) / NB;       // 256
    pfr_fused_kernel<<<nblocks, BT, 0, stream>>>(
        mu_q, std_q, prior, out_samples, out_idx, n_samples, bs);
}

// Round 7
// 14.949 us; speedup vs baseline: 1.6388x; 1.0911x over previous
//
#include <hip/hip_runtime.h>
#include <math.h>

constexpr int DIM = 16;
constexpr int NB  = 4;     // batch rows per block
constexpr int BT  = 512;   // threads per block (8 waves, 2/SIMD, 1 block/CU)
constexpr int NW  = BT / 64;

// ---------------------------------------------------------------------------
// Single fused kernel (one dispatch -- launch overhead dominates this op).
//   score(b,s) = sum_d ( c[b,d]*p^2 + a[b,d]*p ),  p = prior[s,d]
//   a = mu/sigma^2, c = 0.5*(1 - 1/sigma^2)
// (reference's perturbed[b,s] up to a per-b additive constant -- argmax-
//  invariant; normal_log_prob algebraically absorbed: nlp = -0.5 p^2 - K.)
// Coefficients computed cooperatively (64 divides total per block, not per
// thread), broadcast via LDS into per-thread registers.
// ---------------------------------------------------------------------------
__global__ __launch_bounds__(BT) void pfr_fused_kernel(
    const float* __restrict__ mu_q, const float* __restrict__ std_q,
    const float* __restrict__ prior,
    float* __restrict__ out_samples, float* __restrict__ out_idx,
    int n_samples, int bs)
{
    const int b0  = blockIdx.x * NB;
    const int tid = threadIdx.x;

    __shared__ float a_l[NB * DIM];
    __shared__ float c_l[NB * DIM];

    // ---- cooperative coefficient setup: one (r,d) pair per thread<64 ----
    if (tid < NB * DIM) {
        const int gi = b0 * DIM + tid;           // row r = tid/16, dim d = tid%16
        const float sd = std_q[gi];
        const float w  = 1.0f / (sd * sd);       // same expression as R6
        a_l[tid] = mu_q[gi] * w;
        c_l[tid] = 0.5f - 0.5f * w;
    }
    __syncthreads();

    // ---- broadcast-copy coefficients to registers (uniform addr ds_reads) ----
    float a[NB][DIM], c[NB][DIM];
#pragma unroll
    for (int r = 0; r < NB; ++r) {
        const float4* av = reinterpret_cast<const float4*>(a_l + r * DIM);
        const float4* cv = reinterpret_cast<const float4*>(c_l + r * DIM);
#pragma unroll
        for (int i = 0; i < 4; ++i) {
            float4 va = av[i], vc = cv[i];
            a[r][4*i+0] = va.x; a[r][4*i+1] = va.y; a[r][4*i+2] = va.z; a[r][4*i+3] = va.w;
            c[r][4*i+0] = vc.x; c[r][4*i+1] = vc.y; c[r][4*i+2] = vc.z; c[r][4*i+3] = vc.w;
        }
    }

    float best[NB]; int bidx[NB];
#pragma unroll
    for (int r = 0; r < NB; ++r) { best[r] = -INFINITY; bidx[r] = 0x7fffffff; }

    // ---- scan: each thread handles n/BT = 8 sample rows, shared across NB ----
    for (int s = tid; s < n_samples; s += BT) {
        const float4* rp = reinterpret_cast<const float4*>(prior + (size_t)s * DIM);
        float4 q0 = rp[0], q1 = rp[1], q2 = rp[2], q3 = rp[3];
        float p[DIM] = { q0.x, q0.y, q0.z, q0.w,  q1.x, q1.y, q1.z, q1.w,
                         q2.x, q2.y, q2.z, q2.w,  q3.x, q3.y, q3.z, q3.w };
#pragma unroll
        for (int r = 0; r < NB; ++r) {
            float accA = 0.0f, accB = 0.0f;      // two chains, same as R6
#pragma unroll
            for (int d = 0; d < 8; ++d) {
                accA = fmaf(p[d],   fmaf(c[r][d],   p[d],   a[r][d]),   accA);
                accB = fmaf(p[d+8], fmaf(c[r][d+8], p[d+8], a[r][d+8]), accB);
            }
            const float sc = accA + accB;
            // s ascends per thread -> strict '>' keeps first (smallest) idx
            if (sc > best[r]) { best[r] = sc; bidx[r] = s; }
        }
    }

    // ---- wave (64-lane) butterfly, explicit smaller-idx tie-break ----
#pragma unroll
    for (int off = 32; off >= 1; off >>= 1) {
#pragma unroll
        for (int r = 0; r < NB; ++r) {
            const float ob = __shfl_xor(best[r], off, 64);
            const int   oi = __shfl_xor(bidx[r], off, 64);
            if (ob > best[r] || (ob == best[r] && oi < bidx[r])) {
                best[r] = ob; bidx[r] = oi;
            }
        }
    }

    // ---- cross-wave merge via tiny LDS ----
    __shared__ float wv[NW][NB];
    __shared__ int   wi[NW][NB];
    const int wave = tid >> 6;
    if ((tid & 63) == 0) {
#pragma unroll
        for (int r = 0; r < NB; ++r) { wv[wave][r] = best[r]; wi[wave][r] = bidx[r]; }
    }
    __syncthreads();

    if (tid < NB && (b0 + tid) < bs) {
        float bb = wv[0][tid]; int bbi = wi[0][tid];
#pragma unroll
        for (int w = 1; w < NW; ++w) {
            const float ob = wv[w][tid]; const int oi = wi[w][tid];
            if (ob > bb || (ob == bb && oi < bbi)) { bb = ob; bbi = oi; }
        }
        out_idx[b0 + tid] = (float)bbi;
        const float4* r4 = reinterpret_cast<const float4*>(prior + (size_t)bbi * DIM);
        float4* o = reinterpret_cast<float4*>(out_samples + (size_t)(b0 + tid) * DIM);
        o[0] = r4[0]; o[1] = r4[1]; o[2] = r4[2]; o[3] = r4[3];
    }
}

extern "C" void kernel_launch(void* const* d_in, const int* in_sizes, int n_in,
                              void* d_out, int out_size, void* d_ws, size_t ws_size,
                              hipStream_t stream)
{
    const float* mu_q  = (const float*)d_in[0];   // [bs,16]
    const float* std_q = (const float*)d_in[1];   // [bs,16]
    const float* prior = (const float*)d_in[2];   // [n,16]
    // d_in[3] (normal_log_prob) algebraically absorbed -- unused.

    const int bs        = in_sizes[0] / DIM;      // 1024
    const int n_samples = in_sizes[2] / DIM;      // 4096

    float* out_samples = (float*)d_out;                       // [bs,16]
    float* out_idx     = (float*)d_out + (size_t)bs * DIM;    // [bs]

    const int nblocks = (bs + NB - 1) / NB;       // 256
    pfr_fused_kernel<<<nblocks, BT, 0, stream>>>(
        mu_q, std_q, prior, out_samples, out_idx, n_samples, bs);
}

// Round 8
// 13.420 us; speedup vs baseline: 1.8256x; 1.1140x over previous
//
#include <hip/hip_runtime.h>
#include <math.h>

constexpr int DIM = 16;
constexpr int NB  = 4;     // batch rows per block
constexpr int BT  = 512;   // threads per block (8 waves, 2/SIMD, 1 block/CU)
constexpr int NW  = BT / 64;

typedef float v2f __attribute__((ext_vector_type(2)));

// ---------------------------------------------------------------------------
// Single fused kernel (one dispatch -- launch overhead dominates this op).
//   score(b,s) = sum_d ( c[b,d]*p^2 + a[b,d]*p ),  p = prior[s,d]
//   a = mu/sigma^2, c = 0.5*(1 - 1/sigma^2)
// (reference's perturbed[b,s] up to a per-b additive constant -- argmax-
//  invariant; normal_log_prob algebraically absorbed: nlp = -0.5 p^2 - K.)
// Inner product issued as v_pk_fma_f32 (2 f32 FMAs/instr) on even/odd dim
// pairs -- halves VALU issue count of the FMA floor.
// ---------------------------------------------------------------------------
__global__ __launch_bounds__(BT) void pfr_fused_kernel(
    const float* __restrict__ mu_q, const float* __restrict__ std_q,
    const float* __restrict__ prior,
    float* __restrict__ out_samples, float* __restrict__ out_idx,
    int n_samples, int bs)
{
    const int b0  = blockIdx.x * NB;
    const int tid = threadIdx.x;

    __shared__ float a_l[NB * DIM];
    __shared__ float c_l[NB * DIM];

    // ---- cooperative coefficient setup: one (r,d) pair per thread<64 ----
    if (tid < NB * DIM) {
        const int gi = b0 * DIM + tid;
        const float sd = std_q[gi];
        const float w  = 1.0f / (sd * sd);
        a_l[tid] = mu_q[gi] * w;
        c_l[tid] = 0.5f - 0.5f * w;
    }
    __syncthreads();

    // ---- broadcast coefficients to registers as even/odd v2f pairs ----
    v2f a2[NB][8], c2[NB][8];
#pragma unroll
    for (int r = 0; r < NB; ++r) {
        const float4* av = reinterpret_cast<const float4*>(a_l + r * DIM);
        const float4* cv = reinterpret_cast<const float4*>(c_l + r * DIM);
#pragma unroll
        for (int i = 0; i < 4; ++i) {
            float4 va = av[i], vc = cv[i];
            a2[r][2*i+0] = (v2f){va.x, va.y};  a2[r][2*i+1] = (v2f){va.z, va.w};
            c2[r][2*i+0] = (v2f){vc.x, vc.y};  c2[r][2*i+1] = (v2f){vc.z, vc.w};
        }
    }

    float best[NB]; int bidx[NB];
#pragma unroll
    for (int r = 0; r < NB; ++r) { best[r] = -INFINITY; bidx[r] = 0x7fffffff; }

    // ---- scan: each thread handles n/BT sample rows, shared across NB ----
    const int iters = n_samples / BT;            // 8 for n=4096
    for (int k = 0; k < iters; ++k) {
        const int s = tid + k * BT;
        const float4* rp = reinterpret_cast<const float4*>(prior + (size_t)s * DIM);
        float4 q0 = rp[0], q1 = rp[1], q2 = rp[2], q3 = rp[3];
        v2f p2[8] = { (v2f){q0.x, q0.y}, (v2f){q0.z, q0.w},
                      (v2f){q1.x, q1.y}, (v2f){q1.z, q1.w},
                      (v2f){q2.x, q2.y}, (v2f){q2.z, q2.w},
                      (v2f){q3.x, q3.y}, (v2f){q3.z, q3.w} };
#pragma unroll
        for (int r = 0; r < NB; ++r) {
            v2f acc = (v2f){0.0f, 0.0f};
#pragma unroll
            for (int i = 0; i < 8; ++i) {
                // acc += p * (c*p + a)   -- both as v_pk_fma_f32
                v2f t = __builtin_elementwise_fma(c2[r][i], p2[i], a2[r][i]);
                acc   = __builtin_elementwise_fma(p2[i], t, acc);
            }
            const float sc = acc.x + acc.y;
            // s ascends per thread -> strict '>' keeps first (smallest) idx
            if (sc > best[r]) { best[r] = sc; bidx[r] = s; }
        }
    }

    // ---- wave (64-lane) butterfly, explicit smaller-idx tie-break ----
#pragma unroll
    for (int off = 32; off >= 1; off >>= 1) {
#pragma unroll
        for (int r = 0; r < NB; ++r) {
            const float ob = __shfl_xor(best[r], off, 64);
            const int   oi = __shfl_xor(bidx[r], off, 64);
            if (ob > best[r] || (ob == best[r] && oi < bidx[r])) {
                best[r] = ob; bidx[r] = oi;
            }
        }
    }

    // ---- cross-wave merge via tiny LDS ----
    __shared__ float wv[NW][NB];
    __shared__ int   wi[NW][NB];
    const int wave = tid >> 6;
    if ((tid & 63) == 0) {
#pragma unroll
        for (int r = 0; r < NB; ++r) { wv[wave][r] = best[r]; wi[wave][r] = bidx[r]; }
    }
    __syncthreads();

    if (tid < NB && (b0 + tid) < bs) {
        float bb = wv[0][tid]; int bbi = wi[0][tid];
#pragma unroll
        for (int w = 1; w < NW; ++w) {
            const float ob = wv[w][tid]; const int oi = wi[w][tid];
            if (ob > bb || (ob == bb && oi < bbi)) { bb = ob; bbi = oi; }
        }
        out_idx[b0 + tid] = (float)bbi;
        const float4* r4 = reinterpret_cast<const float4*>(prior + (size_t)bbi * DIM);
        float4* o = reinterpret_cast<float4*>(out_samples + (size_t)(b0 + tid) * DIM);
        o[0] = r4[0]; o[1] = r4[1]; o[2] = r4[2]; o[3] = r4[3];
    }
}

extern "C" void kernel_launch(void* const* d_in, const int* in_sizes, int n_in,
                              void* d_out, int out_size, void* d_ws, size_t ws_size,
                              hipStream_t stream)
{
    const float* mu_q  = (const float*)d_in[0];   // [bs,16]
    const float* std_q = (const float*)d_in[1];   // [bs,16]
    const float* prior = (const float*)d_in[2];   // [n,16]
    // d_in[3] (normal_log_prob) algebraically absorbed -- unused.

    const int bs        = in_sizes[0] / DIM;      // 1024
    const int n_samples = in_sizes[2] / DIM;      // 4096

    float* out_samples = (float*)d_out;                       // [bs,16]
    float* out_idx     = (float*)d_out + (size_t)bs * DIM;    // [bs]

    const int nblocks = (bs + NB - 1) / NB;       // 256
    pfr_fused_kernel<<<nblocks, BT, 0, stream>>>(
        mu_q, std_q, prior, out_samples, out_idx, n_samples, bs);
}